// Round 11
// baseline (673.767 us; speedup 1.0000x reference)
//
#include <hip/hip_runtime.h>
#include <hip/hip_bf16.h>

typedef short bf16x8 __attribute__((ext_vector_type(8)));
typedef float f32x4 __attribute__((ext_vector_type(4)));
typedef float f32x2 __attribute__((ext_vector_type(2)));

#define BKT_SHIFT 9
#define BKT_RANGE 512          // nodes per bucket
#define MAXBKT 256             // N <= 131072 (src packs in 17 bits)
#define NPW 8                  // nodes per wave in striped agg

__device__ __forceinline__ float bf2f(unsigned short u){
  union { unsigned int i; float f; } v; v.i = ((unsigned int)u)<<16; return v.f;
}
__device__ __forceinline__ unsigned short f2bf(float f){
  union { float f; unsigned int i; } v; v.f = f;
  unsigned int i = v.i;
  return (unsigned short)((i + 0x7fffu + ((i>>16)&1u)) >> 16);  // RNE
}
// unpack 2 packed bf16 into float2 {lo, hi}: 2 VALU (shl, and)
__device__ __forceinline__ f32x2 up2(unsigned int v){
  union { unsigned int i; float f; } lo, hi;
  lo.i = v << 16; hi.i = v & 0xffff0000u;
  return (f32x2){lo.f, hi.f};
}

// ---------------- bucket-sort CSR build (R7-measured-best structure) ----------------
// B1: per-block LDS histogram of dst-buckets -> global bucket counts
__global__ void k_bcount(const int* dst, int* gcount, int ne, int nbk){
  __shared__ int cnt[MAXBKT];
  int tid = threadIdx.x;
  if(tid < nbk) cnt[tid] = 0;
  __syncthreads();
  int base = blockIdx.x * 4096;
#pragma unroll
  for(int i=0;i<16;++i){
    int e = base + i*256 + tid;
    if(e < ne) atomicAdd(&cnt[dst[e] >> BKT_SHIFT], 1);
  }
  __syncthreads();
  if(tid < nbk && cnt[tid] > 0) atomicAdd(&gcount[tid], cnt[tid]);
}

// B3 (+fused prep): blocks [0,nch): scatter packed (src | dloc<<17) into ebuf;
// blocks [nch, nch+256): wcat; blocks [nch+256, ...): cast_x.
__global__ void k_bscatter_prep(const int* src, const int* dst, const int* gcount,
                                int* gcur0, unsigned int* ebuf, int ne, int nbk, int nch,
                                const float* emb, const int* n_id, unsigned short* A0,
                                const float* Wl0, const float* Wr0, unsigned short* wc0,
                                const float* Wl1, const float* Wr1, unsigned short* wc1,
                                int n){
  int b = blockIdx.x;
  int tid = threadIdx.x;
  if(b >= nch){
    int pb = b - nch;
    if(pb < 256){
      const float* Wl = (pb < 128) ? Wl0 : Wl1;
      const float* Wr = (pb < 128) ? Wr0 : Wr1;
      unsigned short* wc = (pb < 128) ? wc0 : wc1;
      int i = (pb & 127)*256 + tid;
      int nn = i >> 8, k = i & 255;
      float v = (k<128) ? Wl[nn*128 + k] : Wr[nn*128 + k - 128];
      wc[i] = f2bf(v);
    } else {
      int gid = (pb-256)*256 + tid;
      int row = gid >> 5, c4 = (gid & 31) * 4;
      if(row >= n) return;
      float4 v = *(const float4*)&emb[(long)n_id[row]*128 + c4];
      ushort4 o;
      o.x = f2bf(v.x); o.y = f2bf(v.y); o.z = f2bf(v.z); o.w = f2bf(v.w);
      *(ushort4*)&A0[(long)row*256 + 128 + c4] = o;
    }
    return;
  }
  __shared__ int cnt[MAXBKT];
  __shared__ int runbase[MAXBKT];
  __shared__ int sg[MAXBKT];
  cnt[tid] = 0;
  sg[tid] = (tid < nbk) ? gcount[tid] : 0;
  __syncthreads();
  int base = b * 4096;
  int pk[16], bk[16], re[16];
#pragma unroll
  for(int i=0;i<16;++i){
    int e = base + i*256 + tid;
    if(e < ne){
      int d = dst[e];
      bk[i] = d >> BKT_SHIFT;
      pk[i] = (unsigned)src[e] | ((unsigned)(d & (BKT_RANGE-1)) << 17);
      re[i] = atomicAdd(&cnt[bk[i]], 1);
    } else bk[i] = -1;
  }
  // local exclusive scan of gcount -> bucket base
  int myv = sg[tid];
  __syncthreads();
  for(int off=1; off<256; off<<=1){
    int a = (tid>=off) ? sg[tid-off] : 0;
    __syncthreads();
    sg[tid] += a;
    __syncthreads();
  }
  if(tid < nbk)
    runbase[tid] = (sg[tid] - myv) + (cnt[tid] ? atomicAdd(&gcur0[tid], cnt[tid]) : 0);
  __syncthreads();
#pragma unroll
  for(int i=0;i<16;++i){
    if(bk[i] >= 0) ebuf[runbase[bk[i]] + re[i]] = pk[i];
  }
}

// B4: per-bucket counting sort -> csr + row_off. grid = nbk, block = 512.
__global__ void k_bsort(const unsigned int* ebuf, const int* gcount,
                        int* csr, int* row_off, int n, int ne, int nbk){
  __shared__ int sg[MAXBKT];
  __shared__ int h[BKT_RANGE];
  __shared__ int cur[BKT_RANGE];
  __shared__ int sm[512];
  int t = threadIdx.x;
  int k = blockIdx.x;
  // local exclusive scan of gcount (threads <256 work, all sync)
  if(t < MAXBKT) sg[t] = (t < nbk) ? gcount[t] : 0;
  __syncthreads();
  for(int off=1; off<256; off<<=1){
    int a = (t>=off && t<256) ? sg[t-off] : 0;
    __syncthreads();
    if(t<256) sg[t] += a;
    __syncthreads();
  }
  int beg = sg[k] - gcount[k];
  int end = sg[k];
  int lo = k << BKT_SHIFT;
  h[t] = 0;
  __syncthreads();
  for(int e = beg + t; e < end; e += 512)
    atomicAdd(&h[ebuf[e] >> 17], 1);
  __syncthreads();
  int v = h[t];
  sm[t] = v;
  __syncthreads();
  for(int off=1; off<512; off<<=1){
    int a = (t>=off) ? sm[t-off] : 0;
    __syncthreads();
    sm[t] += a;
    __syncthreads();
  }
  int excl = beg + sm[t] - v;
  cur[t] = excl;
  if(lo + t < n) row_off[lo + t] = excl;
  if(k == nbk-1 && t == 0) row_off[n] = ne;
  __syncthreads();
  for(int e = beg + t; e < end; e += 512){
    unsigned int p = ebuf[e];
    int pos = atomicAdd(&cur[p >> 17], 1);
    csr[pos] = (int)(p & 0x1FFFFu);
  }
}

// ---------------- mean aggregation: XCD-striped columns ----------------
// stripe s = blockIdx&7 -> XCD s (round-robin dispatch). Each XCD touches only
// bytes [s*32, s*32+32) of every x-row: working set 3.2MB < 4MB L2 -> L2-resident.
// csr reads + mean stores are non-temporal (no L2 allocate) to keep L2 clean.
// Wave: 8 edge-slots x 8 byte-lanes; 2-batch (16-edge) unrolled inner loop.
__global__ void k_agg(const unsigned short* X, unsigned short* Mout,
                      const int* row_off, const int* csr, int n){
  int s = blockIdx.x & 7;
  int chunk = blockIdx.x >> 3;
  int wv = threadIdx.x >> 6;
  int lane = threadIdx.x & 63;
  int eg = lane >> 3;                 // edge slot 0..7
  int bl = lane & 7;                  // 4B-lane within the 32B stripe
  int n0 = __builtin_amdgcn_readfirstlane((chunk*4 + wv) * NPW);
  const char* Xs = (const char*)X + 256 + s*32 + bl*4;   // lane's bytes in x-half
  char* Ms = (char*)Mout + s*32 + bl*4;                  // lane's bytes in mean-half
#pragma unroll 1
  for(int i=0; i<NPW; ++i){
    int w = n0 + i;
    if(w >= n) return;
    int beg = row_off[w], end = row_off[w+1];
    int deg = end - beg;
    int c1 = deg - 1;
    f32x2 acc = {0.f, 0.f};
#pragma unroll 1
    for(int base=0; base<deg; base+=16){
      int e0 = base + eg, e1 = base + 8 + eg;
      int i0 = e0 > c1 ? c1 : e0;
      int i1 = e1 > c1 ? c1 : e1;
      int x0 = __builtin_nontemporal_load(&csr[beg + i0]);
      int x1 = __builtin_nontemporal_load(&csr[beg + i1]);
      unsigned int v0 = *(const unsigned int*)(Xs + (long)x0*512);
      unsigned int v1 = *(const unsigned int*)(Xs + (long)x1*512);
      if(e0 > c1) v0 = 0;
      if(e1 > c1) v1 = 0;
      acc += up2(v0);
      acc += up2(v1);
    }
    // reduce across the 8 edge slots (lane bits 3,4,5)
#pragma unroll
    for(int off=8; off<64; off<<=1){
      acc[0] += __shfl_xor(acc[0], off);
      acc[1] += __shfl_xor(acc[1], off);
    }
    if(eg == 0){
      float inv = (deg>0) ? 1.0f/(float)deg : 0.f;
      unsigned int o = ((unsigned)f2bf(acc[1]*inv) << 16) | f2bf(acc[0]*inv);
      __builtin_nontemporal_store(o, (unsigned int*)(Ms + (long)w*512));
    }
  }
}

// ---------------- GEMM: C[M,128] = A[M,256] @ Wcat^T + bias ----------------
// block = 256 thr = 4 waves; 256 rows per block (4 row-tiles of 64), W staged once.
template<int RELU, int OUTSTRIDE, int OUTOFF>
__global__ __launch_bounds__(256,2) void k_gemm(const unsigned short* A,
                                                const unsigned short* wc,
                                                const float* bias,
                                                unsigned short* out, int nrows){
  __shared__ unsigned short Wl[32768];   // 128 rows x 256 cols bf16 = 64KB
  int tid = threadIdx.x;
  // stage W into LDS with st-swizzle: byte ^= (row&7)<<4
  for(int it=0; it<16; ++it){
    int idx  = it*256 + tid;       // 16B chunk id, 4096 total
    int byte = idx*16;
    int row  = byte >> 9;
    int swz  = byte ^ ((row & 7) << 4);
    *(uint4*)((char*)Wl + swz) = *(const uint4*)((const char*)wc + byte);
  }
  __syncthreads();

  int lane = tid & 63, wv = tid >> 6;
  float bs[8];
#pragma unroll
  for(int nf=0; nf<8; ++nf) bs[nf] = bias[nf*16 + (lane & 15)];

  for(int t=0; t<4; ++t){
    int rowA = blockIdx.x*256 + t*64 + wv*16 + (lane & 15);
    int rcl  = rowA < nrows ? rowA : nrows-1;
    const char* Ab = (const char*)(A + (long)rcl*256) + ((lane>>4)*16);
    bf16x8 a[8];
#pragma unroll
    for(int k=0;k<8;++k) a[k] = *(const bf16x8*)(Ab + k*64);

    f32x4 acc[8];
#pragma unroll
    for(int i=0;i<8;++i) acc[i] = (f32x4){0.f,0.f,0.f,0.f};

#pragma unroll
    for(int nf=0; nf<8; ++nf){
      int rw = nf*16 + (lane & 15);
#pragma unroll
      for(int k=0;k<8;++k){
        int byte = (rw*512 + k*64 + (lane>>4)*16) ^ ((rw & 7) << 4);
        bf16x8 b = *(const bf16x8*)((const char*)Wl + byte);
        acc[nf] = __builtin_amdgcn_mfma_f32_16x16x32_bf16(a[k], b, acc[nf], 0, 0, 0);
      }
    }

    int rbase = blockIdx.x*256 + t*64 + wv*16 + (lane>>4)*4;
#pragma unroll
    for(int nf=0; nf<8; ++nf){
      int col = nf*16 + (lane & 15);
#pragma unroll
      for(int r=0;r<4;++r){
        int row = rbase + r;
        if(row < nrows){
          float v = acc[nf][r] + bs[nf];
          if(RELU) v = v > 0.f ? v : 0.f;
          out[(long)row*OUTSTRIDE + OUTOFF + col] = f2bf(v);
        }
      }
    }
  }
}

// ---------------- edge-label dot: 4 pairs per wave, 16 lanes x 16B per row ----------------
__global__ void k_dot(const unsigned short* z, const int* s, const int* d,
                      float* out, int nl){
  int wv = (blockIdx.x*256 + threadIdx.x) >> 6;   // wave id
  int lane = threadIdx.x & 63;
  int g = lane >> 4;                               // group 0..3 (one pair each)
  int gl = lane & 15;                              // lane within group
  int pi = wv*4 + g;
  float acc = 0.f;
  if(pi < nl){
    int si = s[pi], di = d[pi];
    bf16x8 va = *(const bf16x8*)&z[(long)si*128 + gl*8];
    bf16x8 vb = *(const bf16x8*)&z[(long)di*128 + gl*8];
#pragma unroll
    for(int i=0;i<8;++i)
      acc += bf2f((unsigned short)va[i]) * bf2f((unsigned short)vb[i]);
#pragma unroll
    for(int off=1; off<16; off<<=1)
      acc += __shfl_xor(acc, off, 16);
    if(gl==0) out[pi] = acc;
  }
}

extern "C" void kernel_launch(void* const* d_in, const int* in_sizes, int n_in,
                              void* d_out, int out_size, void* d_ws, size_t ws_size,
                              hipStream_t stream){
  const int N  = in_sizes[0];
  const int NE = in_sizes[1] / 2;
  const int NL = in_sizes[2] / 2;
  const int*   n_id = (const int*)d_in[0];
  const int*   src  = (const int*)d_in[1];
  const int*   dst  = src + NE;
  const int*   ls   = (const int*)d_in[2];
  const int*   ld   = ls + NL;
  const float* emb  = (const float*)d_in[3];
  const float* Wl0  = (const float*)d_in[4];
  const float* bl0  = (const float*)d_in[5];
  const float* Wr0  = (const float*)d_in[6];
  const float* Wl1  = (const float*)d_in[7];
  const float* bl1  = (const float*)d_in[8];
  const float* Wr1  = (const float*)d_in[9];
  float* out = (float*)d_out;

  char* ws = (char*)d_ws;
  size_t off = 0;
  auto alloc = [&](size_t bytes)->char*{
    char* p = ws + off;
    off = (off + bytes + 255) & ~(size_t)255;
    return p;
  };
  unsigned short* A0   = (unsigned short*)alloc((size_t)N*256*2);   // [mean0|x]
  unsigned short* A1   = (unsigned short*)alloc((size_t)N*256*2);   // [mean1|h]
  int* row_off         = (int*)alloc((size_t)(N+1)*4);
  int* csr             = (int*)alloc((size_t)NE*4);
  int* gcount          = (int*)alloc(MAXBKT*4*2);   // gcount | gcur0
  int* gcur0           = gcount + MAXBKT;
  unsigned short* wc0  = (unsigned short*)alloc(128*256*2);
  unsigned short* wc1  = (unsigned short*)alloc(128*256*2);
  unsigned int* ebuf   = (unsigned int*)A1;  // 6.4MB overlay, dead before gemm0
  unsigned short* Z    = A0;                 // reuse A0 for z [N][128]

  const int NBK = (N + BKT_RANGE - 1) >> BKT_SHIFT;   // <= 256
  const int NCH = (NE + 4095) / 4096;
  const int AGG_BLOCKS = 8 * ((N + 4*NPW - 1) / (4*NPW));

  hipMemsetAsync(gcount, 0, MAXBKT*4*2, stream);
  hipLaunchKernelGGL(k_bcount, dim3(NCH), dim3(256), 0, stream, dst, gcount, NE, NBK);
  hipLaunchKernelGGL(k_bscatter_prep, dim3(NCH + 256 + (N*32+255)/256), dim3(256), 0, stream,
                     src, dst, gcount, gcur0, ebuf, NE, NBK, NCH,
                     emb, n_id, A0, Wl0, Wr0, wc0, Wl1, Wr1, wc1, N);
  hipLaunchKernelGGL(k_bsort, dim3(NBK), dim3(512), 0, stream,
                     ebuf, gcount, csr, row_off, N, NE, NBK);
  // layer 0
  hipLaunchKernelGGL(k_agg, dim3(AGG_BLOCKS), dim3(256), 0, stream, A0, A0, row_off, csr, N);
  hipLaunchKernelGGL((k_gemm<1,256,128>), dim3((N+255)/256), dim3(256), 0, stream, A0, wc0, bl0, A1, N);
  // layer 1
  hipLaunchKernelGGL(k_agg, dim3(AGG_BLOCKS), dim3(256), 0, stream, A1, A1, row_off, csr, N);
  hipLaunchKernelGGL((k_gemm<0,128,0>), dim3((N+255)/256), dim3(256), 0, stream, A1, wc1, bl1, Z, N);
  // edge-label dots
  hipLaunchKernelGGL(k_dot, dim3((NL+15)/16), dim3(256), 0, stream, Z, ls, ld, out, NL);
}

// Round 12
// 260.045 us; speedup vs baseline: 2.5910x; 2.5910x over previous
//
#include <hip/hip_runtime.h>
#include <hip/hip_bf16.h>

typedef short bf16x8 __attribute__((ext_vector_type(8)));
typedef float f32x4 __attribute__((ext_vector_type(4)));
typedef float f32x2 __attribute__((ext_vector_type(2)));

#define BKT_SHIFT 9
#define BKT_RANGE 512          // nodes per bucket
#define MAXBKT 256             // N <= 131072 (src packs in 17 bits)

__device__ __forceinline__ float bf2f(unsigned short u){
  union { unsigned int i; float f; } v; v.i = ((unsigned int)u)<<16; return v.f;
}
__device__ __forceinline__ unsigned short f2bf(float f){
  union { float f; unsigned int i; } v; v.f = f;
  unsigned int i = v.i;
  return (unsigned short)((i + 0x7fffu + ((i>>16)&1u)) >> 16);  // RNE
}
// unpack 2 packed bf16 into float2 {lo, hi}: 2 VALU (shl, and)
__device__ __forceinline__ f32x2 up2(unsigned int v){
  union { unsigned int i; float f; } lo, hi;
  lo.i = v << 16; hi.i = v & 0xffff0000u;
  return (f32x2){lo.f, hi.f};
}

// ---------------- bucket-sort CSR build ----------------
// B1: per-block LDS histogram of dst-buckets -> global bucket counts
__global__ void k_bcount(const int* dst, int* gcount, int ne, int nbk){
  __shared__ int cnt[MAXBKT];
  int tid = threadIdx.x;
  if(tid < nbk) cnt[tid] = 0;
  __syncthreads();
  int base = blockIdx.x * 4096;
#pragma unroll
  for(int i=0;i<16;++i){
    int e = base + i*256 + tid;
    if(e < ne) atomicAdd(&cnt[dst[e] >> BKT_SHIFT], 1);
  }
  __syncthreads();
  if(tid < nbk && cnt[tid] > 0) atomicAdd(&gcount[tid], cnt[tid]);
}

// B3 (+fused prep): blocks [0,nch): scatter packed (src | dloc<<17) into ebuf;
// blocks [nch, nch+256): wcat; blocks [nch+256, ...): cast_x.
__global__ void k_bscatter_prep(const int* src, const int* dst, const int* gcount,
                                int* gcur0, unsigned int* ebuf, int ne, int nbk, int nch,
                                const float* emb, const int* n_id, unsigned short* A0,
                                const float* Wl0, const float* Wr0, unsigned short* wc0,
                                const float* Wl1, const float* Wr1, unsigned short* wc1,
                                int n){
  int b = blockIdx.x;
  int tid = threadIdx.x;
  if(b >= nch){
    int pb = b - nch;
    if(pb < 256){
      const float* Wl = (pb < 128) ? Wl0 : Wl1;
      const float* Wr = (pb < 128) ? Wr0 : Wr1;
      unsigned short* wc = (pb < 128) ? wc0 : wc1;
      int i = (pb & 127)*256 + tid;
      int nn = i >> 8, k = i & 255;
      float v = (k<128) ? Wl[nn*128 + k] : Wr[nn*128 + k - 128];
      wc[i] = f2bf(v);
    } else {
      int gid = (pb-256)*256 + tid;
      int row = gid >> 5, c4 = (gid & 31) * 4;
      if(row >= n) return;
      float4 v = *(const float4*)&emb[(long)n_id[row]*128 + c4];
      ushort4 o;
      o.x = f2bf(v.x); o.y = f2bf(v.y); o.z = f2bf(v.z); o.w = f2bf(v.w);
      *(ushort4*)&A0[(long)row*256 + 128 + c4] = o;
    }
    return;
  }
  __shared__ int cnt[MAXBKT];
  __shared__ int runbase[MAXBKT];
  __shared__ int sg[MAXBKT];
  cnt[tid] = 0;
  sg[tid] = (tid < nbk) ? gcount[tid] : 0;
  __syncthreads();
  int base = b * 4096;
  int pk[16], bk[16], re[16];
#pragma unroll
  for(int i=0;i<16;++i){
    int e = base + i*256 + tid;
    if(e < ne){
      int d = dst[e];
      bk[i] = d >> BKT_SHIFT;
      pk[i] = (unsigned)src[e] | ((unsigned)(d & (BKT_RANGE-1)) << 17);
      re[i] = atomicAdd(&cnt[bk[i]], 1);
    } else bk[i] = -1;
  }
  // local exclusive scan of gcount -> bucket base
  int myv = sg[tid];
  __syncthreads();
  for(int off=1; off<256; off<<=1){
    int a = (tid>=off) ? sg[tid-off] : 0;
    __syncthreads();
    sg[tid] += a;
    __syncthreads();
  }
  if(tid < nbk)
    runbase[tid] = (sg[tid] - myv) + (cnt[tid] ? atomicAdd(&gcur0[tid], cnt[tid]) : 0);
  __syncthreads();
#pragma unroll
  for(int i=0;i<16;++i){
    if(bk[i] >= 0) ebuf[runbase[bk[i]] + re[i]] = pk[i];
  }
}

// B4: per-bucket counting sort -> csr + row_off. grid = nbk, block = 512.
__global__ void k_bsort(const unsigned int* ebuf, const int* gcount,
                        int* csr, int* row_off, int n, int ne, int nbk){
  __shared__ int sg[MAXBKT];
  __shared__ int h[BKT_RANGE];
  __shared__ int cur[BKT_RANGE];
  __shared__ int sm[512];
  int t = threadIdx.x;
  int k = blockIdx.x;
  // local exclusive scan of gcount (threads <256 work, all sync)
  if(t < MAXBKT) sg[t] = (t < nbk) ? gcount[t] : 0;
  __syncthreads();
  for(int off=1; off<256; off<<=1){
    int a = (t>=off && t<256) ? sg[t-off] : 0;
    __syncthreads();
    if(t<256) sg[t] += a;
    __syncthreads();
  }
  int beg = sg[k] - gcount[k];
  int end = sg[k];
  int lo = k << BKT_SHIFT;
  h[t] = 0;
  __syncthreads();
  for(int e = beg + t; e < end; e += 512)
    atomicAdd(&h[ebuf[e] >> 17], 1);
  __syncthreads();
  int v = h[t];
  sm[t] = v;
  __syncthreads();
  for(int off=1; off<512; off<<=1){
    int a = (t>=off) ? sm[t-off] : 0;
    __syncthreads();
    sm[t] += a;
    __syncthreads();
  }
  int excl = beg + sm[t] - v;
  cur[t] = excl;
  if(lo + t < n) row_off[lo + t] = excl;
  if(k == nbk-1 && t == 0) row_off[n] = ne;
  __syncthreads();
  for(int e = beg + t; e < end; e += 512){
    unsigned int p = ebuf[e];
    int pos = atomicAdd(&cur[p >> 17], 1);
    csr[pos] = (int)(p & 0x1FFFFu);
  }
}

// ---------------- mean aggregation: one wave per node, scalar addressing ----------------
// 100K short-lived waves maximize miss-level parallelism (proven best: R4/R6/R10 = 55.8us;
// 4-node/wave = 63.8, fused = 72.5, striped = 262). csr[e] via s_load, row base SGPR.
__global__ void k_agg(const unsigned short* X, unsigned short* Mout,
                      const int* row_off, const int* csr, int n){
  int w = __builtin_amdgcn_readfirstlane((int)((blockIdx.x*blockDim.x + threadIdx.x) >> 6));
  int lane = threadIdx.x & 63;
  if(w >= n) return;
  int beg = row_off[w], end = row_off[w+1];
  int deg = end - beg;
  f32x2 acc = {0.f, 0.f};
  const char* Xb = (const char*)X + 256;     // x-half of the 512B row
  int e = beg;
  for(; e + 8 <= end; e += 8){
    unsigned int v0 = ((const unsigned int*)(Xb + (long)csr[e  ]*512))[lane];
    unsigned int v1 = ((const unsigned int*)(Xb + (long)csr[e+1]*512))[lane];
    unsigned int v2 = ((const unsigned int*)(Xb + (long)csr[e+2]*512))[lane];
    unsigned int v3 = ((const unsigned int*)(Xb + (long)csr[e+3]*512))[lane];
    unsigned int v4 = ((const unsigned int*)(Xb + (long)csr[e+4]*512))[lane];
    unsigned int v5 = ((const unsigned int*)(Xb + (long)csr[e+5]*512))[lane];
    unsigned int v6 = ((const unsigned int*)(Xb + (long)csr[e+6]*512))[lane];
    unsigned int v7 = ((const unsigned int*)(Xb + (long)csr[e+7]*512))[lane];
    acc += up2(v0); acc += up2(v1); acc += up2(v2); acc += up2(v3);
    acc += up2(v4); acc += up2(v5); acc += up2(v6); acc += up2(v7);
  }
  for(; e + 4 <= end; e += 4){
    unsigned int v0 = ((const unsigned int*)(Xb + (long)csr[e  ]*512))[lane];
    unsigned int v1 = ((const unsigned int*)(Xb + (long)csr[e+1]*512))[lane];
    unsigned int v2 = ((const unsigned int*)(Xb + (long)csr[e+2]*512))[lane];
    unsigned int v3 = ((const unsigned int*)(Xb + (long)csr[e+3]*512))[lane];
    acc += up2(v0); acc += up2(v1); acc += up2(v2); acc += up2(v3);
  }
  for(; e < end; ++e){
    unsigned int v = ((const unsigned int*)(Xb + (long)csr[e]*512))[lane];
    acc += up2(v);
  }
  float inv = (deg>0) ? 1.0f/(float)deg : 0.f;
  float a0 = acc[0]*inv, a1 = acc[1]*inv;
  unsigned int o = ((unsigned int)f2bf(a1) << 16) | (unsigned int)f2bf(a0);
  *(unsigned int*)((char*)Mout + (long)w*512 + lane*4) = o;
}

// ---------------- GEMM: C[M,128] = A[M,256] @ Wcat^T + bias ----------------
// block = 256 thr = 4 waves; 256 rows per block (4 row-tiles of 64), W staged once.
template<int RELU, int OUTSTRIDE, int OUTOFF>
__global__ __launch_bounds__(256,2) void k_gemm(const unsigned short* A,
                                                const unsigned short* wc,
                                                const float* bias,
                                                unsigned short* out, int nrows){
  __shared__ unsigned short Wl[32768];   // 128 rows x 256 cols bf16 = 64KB
  int tid = threadIdx.x;
  // stage W into LDS with st-swizzle: byte ^= (row&7)<<4
  for(int it=0; it<16; ++it){
    int idx  = it*256 + tid;       // 16B chunk id, 4096 total
    int byte = idx*16;
    int row  = byte >> 9;
    int swz  = byte ^ ((row & 7) << 4);
    *(uint4*)((char*)Wl + swz) = *(const uint4*)((const char*)wc + byte);
  }
  __syncthreads();

  int lane = tid & 63, wv = tid >> 6;
  float bs[8];
#pragma unroll
  for(int nf=0; nf<8; ++nf) bs[nf] = bias[nf*16 + (lane & 15)];

  for(int t=0; t<4; ++t){
    int rowA = blockIdx.x*256 + t*64 + wv*16 + (lane & 15);
    int rcl  = rowA < nrows ? rowA : nrows-1;
    const char* Ab = (const char*)(A + (long)rcl*256) + ((lane>>4)*16);
    bf16x8 a[8];
#pragma unroll
    for(int k=0;k<8;++k) a[k] = *(const bf16x8*)(Ab + k*64);

    f32x4 acc[8];
#pragma unroll
    for(int i=0;i<8;++i) acc[i] = (f32x4){0.f,0.f,0.f,0.f};

#pragma unroll
    for(int nf=0; nf<8; ++nf){
      int rw = nf*16 + (lane & 15);
#pragma unroll
      for(int k=0;k<8;++k){
        int byte = (rw*512 + k*64 + (lane>>4)*16) ^ ((rw & 7) << 4);
        bf16x8 b = *(const bf16x8*)((const char*)Wl + byte);
        acc[nf] = __builtin_amdgcn_mfma_f32_16x16x32_bf16(a[k], b, acc[nf], 0, 0, 0);
      }
    }

    int rbase = blockIdx.x*256 + t*64 + wv*16 + (lane>>4)*4;
#pragma unroll
    for(int nf=0; nf<8; ++nf){
      int col = nf*16 + (lane & 15);
#pragma unroll
      for(int r=0;r<4;++r){
        int row = rbase + r;
        if(row < nrows){
          float v = acc[nf][r] + bs[nf];
          if(RELU) v = v > 0.f ? v : 0.f;
          out[(long)row*OUTSTRIDE + OUTOFF + col] = f2bf(v);
        }
      }
    }
  }
}

// ---------------- edge-label dot: 4 pairs per wave, 16 lanes x 16B per row ----------------
__global__ void k_dot(const unsigned short* z, const int* s, const int* d,
                      float* out, int nl){
  int wv = (blockIdx.x*256 + threadIdx.x) >> 6;   // wave id
  int lane = threadIdx.x & 63;
  int g = lane >> 4;                               // group 0..3 (one pair each)
  int gl = lane & 15;                              // lane within group
  int pi = wv*4 + g;
  float acc = 0.f;
  if(pi < nl){
    int si = s[pi], di = d[pi];
    bf16x8 va = *(const bf16x8*)&z[(long)si*128 + gl*8];
    bf16x8 vb = *(const bf16x8*)&z[(long)di*128 + gl*8];
#pragma unroll
    for(int i=0;i<8;++i)
      acc += bf2f((unsigned short)va[i]) * bf2f((unsigned short)vb[i]);
#pragma unroll
    for(int off=1; off<16; off<<=1)
      acc += __shfl_xor(acc, off, 16);
    if(gl==0) out[pi] = acc;
  }
}

extern "C" void kernel_launch(void* const* d_in, const int* in_sizes, int n_in,
                              void* d_out, int out_size, void* d_ws, size_t ws_size,
                              hipStream_t stream){
  const int N  = in_sizes[0];
  const int NE = in_sizes[1] / 2;
  const int NL = in_sizes[2] / 2;
  const int*   n_id = (const int*)d_in[0];
  const int*   src  = (const int*)d_in[1];
  const int*   dst  = src + NE;
  const int*   ls   = (const int*)d_in[2];
  const int*   ld   = ls + NL;
  const float* emb  = (const float*)d_in[3];
  const float* Wl0  = (const float*)d_in[4];
  const float* bl0  = (const float*)d_in[5];
  const float* Wr0  = (const float*)d_in[6];
  const float* Wl1  = (const float*)d_in[7];
  const float* bl1  = (const float*)d_in[8];
  const float* Wr1  = (const float*)d_in[9];
  float* out = (float*)d_out;

  char* ws = (char*)d_ws;
  size_t off = 0;
  auto alloc = [&](size_t bytes)->char*{
    char* p = ws + off;
    off = (off + bytes + 255) & ~(size_t)255;
    return p;
  };
  unsigned short* A0   = (unsigned short*)alloc((size_t)N*256*2);   // [mean0|x]
  unsigned short* A1   = (unsigned short*)alloc((size_t)N*256*2);   // [mean1|h]
  int* row_off         = (int*)alloc((size_t)(N+1)*4);
  int* csr             = (int*)alloc((size_t)NE*4);
  int* gcount          = (int*)alloc(MAXBKT*4*2);   // gcount | gcur0
  int* gcur0           = gcount + MAXBKT;
  unsigned short* wc0  = (unsigned short*)alloc(128*256*2);
  unsigned short* wc1  = (unsigned short*)alloc(128*256*2);
  unsigned int* ebuf   = (unsigned int*)A1;  // 6.4MB overlay, dead before gemm0
  unsigned short* Z    = A0;                 // reuse A0 for z [N][128]

  const int NBK = (N + BKT_RANGE - 1) >> BKT_SHIFT;   // <= 256
  const int NCH = (NE + 4095) / 4096;

  hipMemsetAsync(gcount, 0, MAXBKT*4*2, stream);
  hipLaunchKernelGGL(k_bcount, dim3(NCH), dim3(256), 0, stream, dst, gcount, NE, NBK);
  hipLaunchKernelGGL(k_bscatter_prep, dim3(NCH + 256 + (N*32+255)/256), dim3(256), 0, stream,
                     src, dst, gcount, gcur0, ebuf, NE, NBK, NCH,
                     emb, n_id, A0, Wl0, Wr0, wc0, Wl1, Wr1, wc1, N);
  hipLaunchKernelGGL(k_bsort, dim3(NBK), dim3(512), 0, stream,
                     ebuf, gcount, csr, row_off, N, NE, NBK);
  // layer 0
  hipLaunchKernelGGL(k_agg, dim3((N*64+255)/256), dim3(256), 0, stream, A0, A0, row_off, csr, N);
  hipLaunchKernelGGL((k_gemm<1,256,128>), dim3((N+255)/256), dim3(256), 0, stream, A0, wc0, bl0, A1, N);
  // layer 1
  hipLaunchKernelGGL(k_agg, dim3((N*64+255)/256), dim3(256), 0, stream, A1, A1, row_off, csr, N);
  hipLaunchKernelGGL((k_gemm<0,128,0>), dim3((N+255)/256), dim3(256), 0, stream, A1, wc1, bl1, Z, N);
  // edge-label dots
  hipLaunchKernelGGL(k_dot, dim3((NL+15)/16), dim3(256), 0, stream, Z, ls, ld, out, NL);
}